// Round 4
// baseline (175.540 us; speedup 1.0000x reference)
//
#include <hip/hip_runtime.h>

typedef float f32x4 __attribute__((ext_vector_type(4)));

namespace {
constexpr int BATCH = 32;
constexpr int H = 192;
constexpr int W = 192;
constexpr int HW = H * W;          // 36864
constexpr int NCLS = 25;
constexpr int LUT = 26 * 25;       // transposed LUT: Kt[idx][lab], 26th col = 0 sentinel

constexpr int OFF_PRED   = 0;
constexpr int OFF_MASKF  = BATCH * 3 * HW;
constexpr int OFF_OMAF   = OFF_MASKF + BATCH * NCLS * HW;
constexpr int OFF_ATTN   = OFF_OMAF + BATCH * HW;
constexpr int OFF_MASKB  = OFF_ATTN + BATCH * HW;
constexpr int OFF_OMAB   = OFF_MASKB + BATCH * NCLS * HW;
constexpr int OFF_OMATTN = OFF_OMAB + BATCH * HW;

constexpr int XG = W / 8;                       // 24 x8-groups per row
constexpr int NTHREADS = BATCH * H * XG;        // 147,456 -> 576 blocks of 256
}  // namespace

__device__ __forceinline__ void nt_store4(float* p, float a, float b, float c, float d) {
    f32x4 v = {a, b, c, d};
    __builtin_nontemporal_store(v, reinterpret_cast<f32x4*>(p));
}

// 16-wide label window covering pixels [x-4, x+12); out-of-row -> sentinel NCLS.
__device__ __forceinline__ void lab_window16(int lw[16], const int* __restrict__ row,
                                             int x, int x8) {
    if (x8 > 0) {
        const int4 a = *reinterpret_cast<const int4*>(row + x - 4);
        lw[0] = a.x; lw[1] = a.y; lw[2] = a.z; lw[3] = a.w;
    } else {
        lw[0] = NCLS; lw[1] = NCLS; lw[2] = NCLS; lw[3] = NCLS;
    }
    {
        const int4 c = *reinterpret_cast<const int4*>(row + x);
        lw[4] = c.x; lw[5] = c.y; lw[6] = c.z; lw[7] = c.w;
        const int4 d = *reinterpret_cast<const int4*>(row + x + 4);
        lw[8] = d.x; lw[9] = d.y; lw[10] = d.z; lw[11] = d.w;
    }
    if (x8 < XG - 1) {
        const int4 e = *reinterpret_cast<const int4*>(row + x + 8);
        lw[12] = e.x; lw[13] = e.y; lw[14] = e.z; lw[15] = e.w;
    } else {
        lw[12] = NCLS; lw[13] = NCLS; lw[14] = NCLS; lw[15] = NCLS;
    }
}

__device__ __forceinline__ void f4_window16(float w[16], const float* __restrict__ row,
                                            int x, int x8, float edge) {
    if (x8 > 0) {
        const float4 a = *reinterpret_cast<const float4*>(row + x - 4);
        w[0] = a.x; w[1] = a.y; w[2] = a.z; w[3] = a.w;
    } else {
        w[0] = edge; w[1] = edge; w[2] = edge; w[3] = edge;
    }
    {
        const float4 c = *reinterpret_cast<const float4*>(row + x);
        w[4] = c.x; w[5] = c.y; w[6] = c.z; w[7] = c.w;
        const float4 d = *reinterpret_cast<const float4*>(row + x + 4);
        w[8] = d.x; w[9] = d.y; w[10] = d.z; w[11] = d.w;
    }
    if (x8 < XG - 1) {
        const float4 e = *reinterpret_cast<const float4*>(row + x + 8);
        w[12] = e.x; w[13] = e.y; w[14] = e.z; w[15] = e.w;
    } else {
        w[12] = edge; w[13] = edge; w[14] = edge; w[15] = edge;
    }
}

// ---------------------------------------------------------------------------
// Kernel 1: one-hot masks (nt stream) + seg/appear/attn.  8 px / thread.
// ---------------------------------------------------------------------------
__global__ __launch_bounds__(256) void k_mask_seg(
    const int* __restrict__ labF, const int* __restrict__ labB,
    const float* __restrict__ mk, float* __restrict__ out)
{
    __shared__ float sk[LUT];
    for (int i = threadIdx.x; i < LUT; i += 256) {
        const int idx = i / 26;
        const int l = i - idx * 26;
        sk[i] = (l < NCLS) ? mk[l * 25 + idx] : 0.0f;  // Kt[idx*26 + lab]
    }
    __syncthreads();

    const int t = blockIdx.x * 256 + threadIdx.x;
    const int x8 = t % XG;
    const int rest = t / XG;
    const int y = rest % H;
    const int b = rest / H;
    const int x = x8 * 8;
    const int pix = b * HW + y * W + x;

    const int4 lf0 = *reinterpret_cast<const int4*>(labF + pix);
    const int4 lf1 = *reinterpret_cast<const int4*>(labF + pix + 4);
    const int4 lb0 = *reinterpret_cast<const int4*>(labB + pix);
    const int4 lb1 = *reinterpret_cast<const int4*>(labB + pix + 4);

    // --- one-hot mask planes: write-once stream, bypass L2 ---
    {
        float* __restrict__ mf = out + OFF_MASKF + b * (NCLS * HW) + y * W + x;
        float* __restrict__ mb = out + OFF_MASKB + b * (NCLS * HW) + y * W + x;
#pragma unroll
        for (int k = 0; k < NCLS; ++k) {
            nt_store4(mf + k * HW, lf0.x == k ? 1.f : 0.f, lf0.y == k ? 1.f : 0.f,
                      lf0.z == k ? 1.f : 0.f, lf0.w == k ? 1.f : 0.f);
            nt_store4(mf + k * HW + 4, lf1.x == k ? 1.f : 0.f, lf1.y == k ? 1.f : 0.f,
                      lf1.z == k ? 1.f : 0.f, lf1.w == k ? 1.f : 0.f);
            nt_store4(mb + k * HW, lb0.x == k ? 1.f : 0.f, lb0.y == k ? 1.f : 0.f,
                      lb0.z == k ? 1.f : 0.f, lb0.w == k ? 1.f : 0.f);
            nt_store4(mb + k * HW + 4, lb1.x == k ? 1.f : 0.f, lb1.y == k ? 1.f : 0.f,
                      lb1.z == k ? 1.f : 0.f, lb1.w == k ? 1.f : 0.f);
        }
    }

    // --- seg via 5x5 label-gather through the LUT ---
    float segf[8] = {}, segb[8] = {};
#pragma unroll
    for (int dy = 0; dy < 5; ++dy) {
        const int yy = y + dy - 2;
        if (yy < 0 || yy >= H) continue;
        int lwF[16], lwB[16];
        lab_window16(lwF, labF + b * HW + yy * W, x, x8);
        lab_window16(lwB, labB + b * HW + yy * W, x, x8);
#pragma unroll
        for (int dx = 0; dx < 5; ++dx) {
            const int base = (dy * 5 + dx) * 26;
#pragma unroll
            for (int i = 0; i < 8; ++i) {
                segf[i] += sk[base + lwF[i + dx + 2]];
                segb[i] += sk[base + lwB[i + dx + 2]];
            }
        }
    }

    float v_omaf[8], v_omab[8], v_at[8], v_omat[8];
#pragma unroll
    for (int i = 0; i < 8; ++i) {
        const float af = fmaxf(1.f - fmaxf(segf[i] - 1.f, 0.f), 0.f);
        const float ab = fmaxf(1.f - fmaxf(segb[i] - 1.f, 0.f), 0.f);
        const float scf = 1.f - fmaxf(1.f - segf[i], 0.f);
        const float scb = 1.f - fmaxf(1.f - segb[i], 0.f);
        const float at = (scf + 1e-5f) / (scf + scb + 2e-5f);
        v_omaf[i] = 1.f - af;
        v_omab[i] = 1.f - ab;
        v_at[i]   = at;
        v_omat[i] = 1.f - at;
    }
    // omaf/omab/attn are re-read by kernel 2 -> normal stores (stay in L2).
    *reinterpret_cast<float4*>(out + OFF_OMAF + pix) =
        make_float4(v_omaf[0], v_omaf[1], v_omaf[2], v_omaf[3]);
    *reinterpret_cast<float4*>(out + OFF_OMAF + pix + 4) =
        make_float4(v_omaf[4], v_omaf[5], v_omaf[6], v_omaf[7]);
    *reinterpret_cast<float4*>(out + OFF_OMAB + pix) =
        make_float4(v_omab[0], v_omab[1], v_omab[2], v_omab[3]);
    *reinterpret_cast<float4*>(out + OFF_OMAB + pix + 4) =
        make_float4(v_omab[4], v_omab[5], v_omab[6], v_omab[7]);
    *reinterpret_cast<float4*>(out + OFF_ATTN + pix) =
        make_float4(v_at[0], v_at[1], v_at[2], v_at[3]);
    *reinterpret_cast<float4*>(out + OFF_ATTN + pix + 4) =
        make_float4(v_at[4], v_at[5], v_at[6], v_at[7]);
    nt_store4(out + OFF_OMATTN + pix, v_omat[0], v_omat[1], v_omat[2], v_omat[3]);
    nt_store4(out + OFF_OMATTN + pix + 4, v_omat[4], v_omat[5], v_omat[6], v_omat[7]);
}

// ---------------------------------------------------------------------------
// Kernel 2: pred = attn*pred_f + (1-attn)*pred_b.  8 px / thread.
// ---------------------------------------------------------------------------
__device__ __forceinline__ void accum_img(
    const float* __restrict__ im, const int* __restrict__ lab,
    const float* __restrict__ omA, const float* sk,
    int b, int y, int x, int x8, float acc[3][8])
{
#pragma unroll
    for (int dy = 0; dy < 5; ++dy) {
        const int yy = y + dy - 2;
        if (yy < 0 || yy >= H) continue;
        const int rowo = b * HW + yy * W;
        const int imo = b * (6 * HW) + 3 * HW + yy * W;  // channels 3..5

        int lw[16];
        lab_window16(lw, lab + rowo, x, x8);
        float aw[16], v0[16], v1[16], v2[16];
        f4_window16(aw, omA + rowo, x, x8, 1.f);   // edge: om=1 -> a=0
        f4_window16(v0, im + imo, x, x8, 0.f);
        f4_window16(v1, im + imo + HW, x, x8, 0.f);
        f4_window16(v2, im + imo + 2 * HW, x, x8, 0.f);
        float a[16];
#pragma unroll
        for (int j = 0; j < 16; ++j) a[j] = 1.f - aw[j];

#pragma unroll
        for (int dx = 0; dx < 5; ++dx) {
            const int base = (dy * 5 + dx) * 26;
#pragma unroll
            for (int i = 0; i < 8; ++i) {
                const int li = i + dx + 2;
                const float w = a[li] * sk[base + lw[li]];
                acc[0][i] = fmaf(w, v0[li], acc[0][i]);
                acc[1][i] = fmaf(w, v1[li], acc[1][i]);
                acc[2][i] = fmaf(w, v2[li], acc[2][i]);
            }
        }
    }
}

__global__ __launch_bounds__(256) void k_pred(
    const float* __restrict__ imF, const float* __restrict__ imB,
    const int* __restrict__ labF, const int* __restrict__ labB,
    const float* __restrict__ mk, float* __restrict__ out)
{
    __shared__ float sk[LUT];
    for (int i = threadIdx.x; i < LUT; i += 256) {
        const int idx = i / 26;
        const int l = i - idx * 26;
        sk[i] = (l < NCLS) ? mk[l * 25 + idx] : 0.0f;
    }
    __syncthreads();

    const int t = blockIdx.x * 256 + threadIdx.x;
    const int x8 = t % XG;
    const int rest = t / XG;
    const int y = rest % H;
    const int b = rest / H;
    const int x = x8 * 8;
    const int pix = b * HW + y * W + x;

    float accf[3][8] = {};
    float accb[3][8] = {};
    accum_img(imF, labF, out + OFF_OMAF, sk, b, y, x, x8, accf);
    accum_img(imB, labB, out + OFF_OMAB, sk, b, y, x, x8, accb);

    const float4 at0 = *reinterpret_cast<const float4*>(out + OFF_ATTN + pix);
    const float4 at1 = *reinterpret_cast<const float4*>(out + OFF_ATTN + pix + 4);
    const float atv[8] = {at0.x, at0.y, at0.z, at0.w, at1.x, at1.y, at1.z, at1.w};

    float* pout = out + OFF_PRED + b * (3 * HW) + y * W + x;
#pragma unroll
    for (int c = 0; c < 3; ++c) {
        float p[8];
#pragma unroll
        for (int i = 0; i < 8; ++i)
            p[i] = atv[i] * accf[c][i] + (1.f - atv[i]) * accb[c][i];
        nt_store4(pout + c * HW, p[0], p[1], p[2], p[3]);
        nt_store4(pout + c * HW + 4, p[4], p[5], p[6], p[7]);
    }
}

extern "C" void kernel_launch(void* const* d_in, const int* in_sizes, int n_in,
                              void* d_out, int out_size, void* d_ws, size_t ws_size,
                              hipStream_t stream) {
    const float* imF  = (const float*)d_in[0];
    const float* imB  = (const float*)d_in[1];
    const int*   labF = (const int*)d_in[2];
    const int*   labB = (const int*)d_in[3];
    const float* mk   = (const float*)d_in[4];
    float* out = (float*)d_out;

    const int grid = NTHREADS / 256;  // 576 blocks, exact
    k_mask_seg<<<grid, 256, 0, stream>>>(labF, labB, mk, out);
    k_pred<<<grid, 256, 0, stream>>>(imF, imB, labF, labB, mk, out);
}

// Round 5
// 90.370 us; speedup vs baseline: 1.9425x; 1.9425x over previous
//
#include <hip/hip_runtime.h>

typedef float f32x4 __attribute__((ext_vector_type(4)));

namespace {
constexpr int BATCH = 32;
constexpr int H = 192;
constexpr int W = 192;
constexpr int HW = H * W;
constexpr int NCLS = 25;
constexpr int LUTN = 26 * 25;   // transposed LUT: sk[tap*26 + lab], col 25 = 0 sentinel

constexpr int OFF_PRED   = 0;
constexpr int OFF_MASKF  = BATCH * 3 * HW;
constexpr int OFF_OMAF   = OFF_MASKF + BATCH * NCLS * HW;
constexpr int OFF_ATTN   = OFF_OMAF + BATCH * HW;
constexpr int OFF_MASKB  = OFF_ATTN + BATCH * HW;
constexpr int OFF_OMAB   = OFF_MASKB + BATCH * NCLS * HW;
constexpr int OFF_OMATTN = OFF_OMAB + BATCH * HW;

constexpr int TX = 64, TY = 16;
constexpr int SROWS = TY + 4;        // 20 staged rows (2 halo each side)
constexpr int SGRP  = TX / 4 + 2;    // 18 staged float4-groups per row (1 halo group each side)
constexpr int XT = W / TX;           // 3
constexpr int YT = H / TY;           // 12
constexpr int NBLK = BATCH * XT * YT;  // 1152 blocks of 256
}  // namespace

__device__ __forceinline__ void nt_store4(float* p, float a, float b, float c, float d) {
    f32x4 v = {a, b, c, d};
    __builtin_nontemporal_store(v, reinterpret_cast<f32x4*>(p));
}

// Guarded 12-wide label window at absolute x (xabs % 4 == 0, 0 <= xabs < W).
__device__ __forceinline__ void lab_win12(int lw[12], const int* __restrict__ row, int xabs) {
    if (xabs >= 4) {
        const int4 a = *reinterpret_cast<const int4*>(row + xabs - 4);
        lw[0] = a.x; lw[1] = a.y; lw[2] = a.z; lw[3] = a.w;
    } else {
        lw[0] = NCLS; lw[1] = NCLS; lw[2] = NCLS; lw[3] = NCLS;
    }
    {
        const int4 c = *reinterpret_cast<const int4*>(row + xabs);
        lw[4] = c.x; lw[5] = c.y; lw[6] = c.z; lw[7] = c.w;
    }
    if (xabs <= W - 8) {
        const int4 e = *reinterpret_cast<const int4*>(row + xabs + 4);
        lw[8] = e.x; lw[9] = e.y; lw[10] = e.z; lw[11] = e.w;
    } else {
        lw[8] = NCLS; lw[9] = NCLS; lw[10] = NCLS; lw[11] = NCLS;
    }
}

__device__ __forceinline__ void f4_win12(float w[12], const float* __restrict__ row, int xabs) {
    if (xabs >= 4) {
        const float4 a = *reinterpret_cast<const float4*>(row + xabs - 4);
        w[0] = a.x; w[1] = a.y; w[2] = a.z; w[3] = a.w;
    } else {
        w[0] = 0.f; w[1] = 0.f; w[2] = 0.f; w[3] = 0.f;
    }
    {
        const float4 c = *reinterpret_cast<const float4*>(row + xabs);
        w[4] = c.x; w[5] = c.y; w[6] = c.z; w[7] = c.w;
    }
    if (xabs <= W - 8) {
        const float4 e = *reinterpret_cast<const float4*>(row + xabs + 4);
        w[8] = e.x; w[9] = e.y; w[10] = e.z; w[11] = e.w;
    } else {
        w[8] = 0.f; w[9] = 0.f; w[10] = 0.f; w[11] = 0.f;
    }
}

// Stage one (row, g) unit: compute appear for 4 px, write packed 2*lab+appear to LDS.
// INTERIOR units additionally write masks / 1-appear / attn / 1-attn and return attn.
template <bool INTERIOR>
__device__ __forceinline__ void stage_unit(
    int row, int g, int b, int tx0, int y0,
    const int* __restrict__ labF, const int* __restrict__ labB,
    const float* __restrict__ sk,
    float (*pF)[SGRP * 4], float (*pB)[SGRP * 4],
    float* __restrict__ out, float at_out[4])
{
    const int yabs = y0 + row - 2;
    const int xabs = tx0 - 4 + 4 * g;
    f32x4 pf = {2.f * NCLS, 2.f * NCLS, 2.f * NCLS, 2.f * NCLS};
    f32x4 pb = pf;

    if (yabs >= 0 && yabs < H && xabs >= 0 && xabs < W) {
        float segf[4] = {0.f, 0.f, 0.f, 0.f};
        float segb[4] = {0.f, 0.f, 0.f, 0.f};
        int lfa[4], lba[4];
        for (int dy = 0; dy < 5; ++dy) {
            const int yy = yabs + dy - 2;
            if (yy < 0 || yy >= H) continue;
            const int* rF = labF + b * HW + yy * W;
            const int* rB = labB + b * HW + yy * W;
            int lwF[12], lwB[12];
            lab_win12(lwF, rF, xabs);
            lab_win12(lwB, rB, xabs);
            if (dy == 2) {
#pragma unroll
                for (int i = 0; i < 4; ++i) { lfa[i] = lwF[4 + i]; lba[i] = lwB[4 + i]; }
            }
#pragma unroll
            for (int dx = 0; dx < 5; ++dx) {
                const int base = (dy * 5 + dx) * 26;
#pragma unroll
                for (int i = 0; i < 4; ++i) {
                    segf[i] += sk[base + lwF[i + dx + 2]];
                    segb[i] += sk[base + lwB[i + dx + 2]];
                }
            }
        }
        float af[4], ab[4];
#pragma unroll
        for (int i = 0; i < 4; ++i) {
            af[i] = fmaxf(1.f - fmaxf(segf[i] - 1.f, 0.f), 0.f);
            ab[i] = fmaxf(1.f - fmaxf(segb[i] - 1.f, 0.f), 0.f);
            pf[i] = 2.f * (float)lfa[i] + af[i];
            pb[i] = 2.f * (float)lba[i] + ab[i];
        }
        if (INTERIOR) {
            const int pix = b * HW + yabs * W + xabs;
            float* __restrict__ mf = out + OFF_MASKF + b * (NCLS * HW) + yabs * W + xabs;
            float* __restrict__ mb = out + OFF_MASKB + b * (NCLS * HW) + yabs * W + xabs;
#pragma unroll
            for (int k = 0; k < NCLS; ++k) {
                nt_store4(mf + k * HW, lfa[0] == k ? 1.f : 0.f, lfa[1] == k ? 1.f : 0.f,
                          lfa[2] == k ? 1.f : 0.f, lfa[3] == k ? 1.f : 0.f);
                nt_store4(mb + k * HW, lba[0] == k ? 1.f : 0.f, lba[1] == k ? 1.f : 0.f,
                          lba[2] == k ? 1.f : 0.f, lba[3] == k ? 1.f : 0.f);
            }
            float at[4], omat[4];
#pragma unroll
            for (int i = 0; i < 4; ++i) {
                const float scf = 1.f - fmaxf(1.f - segf[i], 0.f);
                const float scb = 1.f - fmaxf(1.f - segb[i], 0.f);
                at[i] = (scf + 1e-5f) / (scf + scb + 2e-5f);
                omat[i] = 1.f - at[i];
                at_out[i] = at[i];
            }
            nt_store4(out + OFF_OMAF + pix, 1.f - af[0], 1.f - af[1], 1.f - af[2], 1.f - af[3]);
            nt_store4(out + OFF_OMAB + pix, 1.f - ab[0], 1.f - ab[1], 1.f - ab[2], 1.f - ab[3]);
            nt_store4(out + OFF_ATTN + pix, at[0], at[1], at[2], at[3]);
            nt_store4(out + OFF_OMATTN + pix, omat[0], omat[1], omat[2], omat[3]);
        }
    }
    *reinterpret_cast<f32x4*>(&pF[row][g * 4]) = pf;
    *reinterpret_cast<f32x4*>(&pB[row][g * 4]) = pb;
}

// Conv one image: acc_c[i] += sum_taps appear[j]*K[lab[j]][tap]*im_c[j], LDS-sourced lab/appear.
__device__ __forceinline__ void conv_img(
    const float (*P)[SGRP * 4], const float* __restrict__ im, const float* __restrict__ sk,
    int b, int y, int x, int r_i, int g_i, float acc[3][4])
{
    for (int dy = 0; dy < 5; ++dy) {
        const int yy = y + dy - 2;
        if (yy < 0 || yy >= H) continue;
        const int srow = r_i + dy;
        float pw[12];
        *reinterpret_cast<f32x4*>(&pw[0]) = *reinterpret_cast<const f32x4*>(&P[srow][g_i * 4]);
        *reinterpret_cast<f32x4*>(&pw[4]) = *reinterpret_cast<const f32x4*>(&P[srow][g_i * 4 + 4]);
        *reinterpret_cast<f32x4*>(&pw[8]) = *reinterpret_cast<const f32x4*>(&P[srow][g_i * 4 + 8]);
        int lw[12];
        float aw[12];
#pragma unroll
        for (int j = 2; j < 10; ++j) {   // only indices 2..9 are used by the taps
            const int l = (int)(pw[j] * 0.5f);
            lw[j] = l;
            aw[j] = pw[j] - 2.f * (float)l;
        }
        const int imo = b * (6 * HW) + 3 * HW + yy * W;
        float v0[12], v1[12], v2[12];
        f4_win12(v0, im + imo, x);
        f4_win12(v1, im + imo + HW, x);
        f4_win12(v2, im + imo + 2 * HW, x);
#pragma unroll
        for (int dx = 0; dx < 5; ++dx) {
            const int base = (dy * 5 + dx) * 26;
#pragma unroll
            for (int i = 0; i < 4; ++i) {
                const int li = i + dx + 2;
                const float w = aw[li] * sk[base + lw[li]];
                acc[0][i] = fmaf(w, v0[li], acc[0][i]);
                acc[1][i] = fmaf(w, v1[li], acc[1][i]);
                acc[2][i] = fmaf(w, v2[li], acc[2][i]);
            }
        }
    }
}

__global__ __launch_bounds__(256) void k_fused(
    const float* __restrict__ imF, const float* __restrict__ imB,
    const int* __restrict__ labF, const int* __restrict__ labB,
    const float* __restrict__ mk, float* __restrict__ out)
{
    __shared__ float sk[LUTN];
    __shared__ float pF[SROWS][SGRP * 4];
    __shared__ float pB[SROWS][SGRP * 4];

    for (int i = threadIdx.x; i < LUTN; i += 256) {
        const int tap = i / 26;
        const int l = i - tap * 26;
        sk[i] = (l < NCLS) ? mk[l * 25 + tap] : 0.0f;
    }
    __syncthreads();

    const int blk = blockIdx.x;
    const int bx = blk % XT;
    const int by = (blk / XT) % YT;
    const int b  = blk / (XT * YT);
    const int tx0 = bx * TX;
    const int y0  = by * TY;
    const int t = threadIdx.x;

    const int r_i = t / (TX / 4);   // 0..15
    const int g_i = t % (TX / 4);   // 0..15

    // --- Phase A: stage packed (2*lab + appear) tile; interior also writes outputs ---
    float my_at[4];
    stage_unit<true>(r_i + 2, g_i + 1, b, tx0, y0, labF, labB, sk, pF, pB, out, my_at);
    float dummy[4];
    if (t < 72) {
        const int hr = t / 18;                       // 0..3
        const int row = (hr < 2) ? hr : hr + 16;     // {0,1,18,19}
        stage_unit<false>(row, t % 18, b, tx0, y0, labF, labB, sk, pF, pB, out, dummy);
    } else if (t < 104) {
        const int h = t - 72;
        stage_unit<false>(2 + h / 2, (h & 1) ? (SGRP - 1) : 0, b, tx0, y0, labF, labB, sk,
                          pF, pB, out, dummy);
    }
    __syncthreads();

    // --- Phase B: pred conv from LDS-staged appear/lab + global im windows ---
    const int y = y0 + r_i;
    const int x = tx0 + 4 * g_i;

    float accF[3][4] = {};
    float accB[3][4] = {};
    conv_img(pF, imF, sk, b, y, x, r_i, g_i, accF);
    conv_img(pB, imB, sk, b, y, x, r_i, g_i, accB);

    float* pout = out + OFF_PRED + b * (3 * HW) + y * W + x;
#pragma unroll
    for (int c = 0; c < 3; ++c) {
        float p[4];
#pragma unroll
        for (int i = 0; i < 4; ++i)
            p[i] = my_at[i] * accF[c][i] + (1.f - my_at[i]) * accB[c][i];
        nt_store4(pout + c * HW, p[0], p[1], p[2], p[3]);
    }
}

extern "C" void kernel_launch(void* const* d_in, const int* in_sizes, int n_in,
                              void* d_out, int out_size, void* d_ws, size_t ws_size,
                              hipStream_t stream) {
    const float* imF  = (const float*)d_in[0];
    const float* imB  = (const float*)d_in[1];
    const int*   labF = (const int*)d_in[2];
    const int*   labB = (const int*)d_in[3];
    const float* mk   = (const float*)d_in[4];
    float* out = (float*)d_out;

    k_fused<<<NBLK, 256, 0, stream>>>(imF, imB, labF, labB, mk, out);
}

// Round 6
// 69.480 us; speedup vs baseline: 2.5265x; 1.3007x over previous
//
#include <hip/hip_runtime.h>

typedef float f32x4 __attribute__((ext_vector_type(4)));

namespace {
constexpr int BATCH = 32;
constexpr int H = 192;
constexpr int W = 192;
constexpr int HW = H * W;
constexpr int NCLS = 25;
constexpr int LUTN = 26 * 25;   // transposed LUT: sk[tap*26 + lab], col 25 = 0 sentinel

constexpr int OFF_PRED   = 0;
constexpr int OFF_MASKF  = BATCH * 3 * HW;
constexpr int OFF_OMAF   = OFF_MASKF + BATCH * NCLS * HW;
constexpr int OFF_ATTN   = OFF_OMAF + BATCH * HW;
constexpr int OFF_MASKB  = OFF_ATTN + BATCH * HW;
constexpr int OFF_OMAB   = OFF_MASKB + BATCH * NCLS * HW;
constexpr int OFF_OMATTN = OFF_OMAB + BATCH * HW;

constexpr int TY = 8;            // tile = full width x 8 rows
constexpr int SROWS = TY + 4;    // 12 staged rows
constexpr int SW = W + 8;        // 200 floats per LDS row (4-px sentinel pad each side)
constexpr int GPR = W / 4;       // 48 groups per row
constexpr int NTHR = GPR * TY;   // 384 threads (6 waves)
constexpr int YT = H / TY;       // 24
constexpr int NBLK = BATCH * YT; // 768 blocks = 3 per CU
constexpr float SENT = 2.0f * NCLS;  // packed sentinel: lab=25 (zero LUT col), appear=0
}  // namespace

__device__ __forceinline__ void nt_store4(float* p, float a, float b, float c, float d) {
    f32x4 v = {a, b, c, d};
    __builtin_nontemporal_store(v, reinterpret_cast<f32x4*>(p));
}

// 12-wide label window [xabs-4, xabs+8); out-of-row -> sentinel NCLS.
__device__ __forceinline__ void lab_win12(int lw[12], const int* __restrict__ row, int xabs) {
    if (xabs >= 4) {
        const int4 a = *reinterpret_cast<const int4*>(row + xabs - 4);
        lw[0] = a.x; lw[1] = a.y; lw[2] = a.z; lw[3] = a.w;
    } else {
        lw[0] = NCLS; lw[1] = NCLS; lw[2] = NCLS; lw[3] = NCLS;
    }
    {
        const int4 c = *reinterpret_cast<const int4*>(row + xabs);
        lw[4] = c.x; lw[5] = c.y; lw[6] = c.z; lw[7] = c.w;
    }
    if (xabs <= W - 8) {
        const int4 e = *reinterpret_cast<const int4*>(row + xabs + 4);
        lw[8] = e.x; lw[9] = e.y; lw[10] = e.z; lw[11] = e.w;
    } else {
        lw[8] = NCLS; lw[9] = NCLS; lw[10] = NCLS; lw[11] = NCLS;
    }
}

__device__ __forceinline__ void f4_win12(float w[12], const float* __restrict__ row, int xabs) {
    if (xabs >= 4) {
        const float4 a = *reinterpret_cast<const float4*>(row + xabs - 4);
        w[0] = a.x; w[1] = a.y; w[2] = a.z; w[3] = a.w;
    } else {
        w[0] = 0.f; w[1] = 0.f; w[2] = 0.f; w[3] = 0.f;
    }
    {
        const float4 c = *reinterpret_cast<const float4*>(row + xabs);
        w[4] = c.x; w[5] = c.y; w[6] = c.z; w[7] = c.w;
    }
    if (xabs <= W - 8) {
        const float4 e = *reinterpret_cast<const float4*>(row + xabs + 4);
        w[8] = e.x; w[9] = e.y; w[10] = e.z; w[11] = e.w;
    } else {
        w[8] = 0.f; w[9] = 0.f; w[10] = 0.f; w[11] = 0.f;
    }
}

// Compute seg/appear for the 4 px at (y0+row-2, 4g); write packed 2*lab+appear to LDS.
// INTERIOR also writes the 4 small aux outputs and returns attn + center labels.
template <bool INTERIOR>
__device__ __forceinline__ void stage_unit(
    int row, int g, int b, int y0,
    const int* __restrict__ labF, const int* __restrict__ labB,
    const float* __restrict__ sk,
    float (*pF)[SW], float (*pB)[SW],
    float* __restrict__ out, float at_out[4], int lf_out[4], int lb_out[4])
{
    const int yabs = y0 + row - 2;
    const int xabs = 4 * g;
    f32x4 pf = {SENT, SENT, SENT, SENT};
    f32x4 pb = pf;

    if (yabs >= 0 && yabs < H) {
        float segf[4] = {0.f, 0.f, 0.f, 0.f};
        float segb[4] = {0.f, 0.f, 0.f, 0.f};
        int lfa[4], lba[4];
        for (int dy = 0; dy < 5; ++dy) {
            const int yy = yabs + dy - 2;
            if (yy < 0 || yy >= H) continue;
            int lwF[12], lwB[12];
            lab_win12(lwF, labF + b * HW + yy * W, xabs);
            lab_win12(lwB, labB + b * HW + yy * W, xabs);
            if (dy == 2) {
#pragma unroll
                for (int i = 0; i < 4; ++i) { lfa[i] = lwF[4 + i]; lba[i] = lwB[4 + i]; }
            }
#pragma unroll
            for (int dx = 0; dx < 5; ++dx) {
                const int base = (dy * 5 + dx) * 26;
#pragma unroll
                for (int i = 0; i < 4; ++i) {
                    segf[i] += sk[base + lwF[i + dx + 2]];
                    segb[i] += sk[base + lwB[i + dx + 2]];
                }
            }
        }
        float af[4], ab[4];
#pragma unroll
        for (int i = 0; i < 4; ++i) {
            af[i] = fmaxf(1.f - fmaxf(segf[i] - 1.f, 0.f), 0.f);
            ab[i] = fmaxf(1.f - fmaxf(segb[i] - 1.f, 0.f), 0.f);
            pf[i] = 2.f * (float)lfa[i] + af[i];
            pb[i] = 2.f * (float)lba[i] + ab[i];
        }
        if (INTERIOR) {
            const int pix = b * HW + yabs * W + xabs;
            float at[4];
#pragma unroll
            for (int i = 0; i < 4; ++i) {
                const float scf = 1.f - fmaxf(1.f - segf[i], 0.f);
                const float scb = 1.f - fmaxf(1.f - segb[i], 0.f);
                at[i] = (scf + 1e-5f) / (scf + scb + 2e-5f);
                at_out[i] = at[i];
                lf_out[i] = lfa[i];
                lb_out[i] = lba[i];
            }
            nt_store4(out + OFF_OMAF + pix, 1.f - af[0], 1.f - af[1], 1.f - af[2], 1.f - af[3]);
            nt_store4(out + OFF_OMAB + pix, 1.f - ab[0], 1.f - ab[1], 1.f - ab[2], 1.f - ab[3]);
            nt_store4(out + OFF_ATTN + pix, at[0], at[1], at[2], at[3]);
            nt_store4(out + OFF_OMATTN + pix, 1.f - at[0], 1.f - at[1], 1.f - at[2], 1.f - at[3]);
        }
    }
    *reinterpret_cast<f32x4*>(&pF[row][4 + 4 * g]) = pf;
    *reinterpret_cast<f32x4*>(&pB[row][4 + 4 * g]) = pb;
}

// Conv one image, with that image's 25 one-hot mask-plane stores interleaved
// (5 planes per dy iteration) so the nt store stream overlaps the compute.
__device__ __forceinline__ void conv_img(
    const float (*P)[SW], const float* __restrict__ im,
    const float* __restrict__ sk, const int lab4[4],
    float* __restrict__ mbase,
    int b, int y, int x, int r_i, int g_i, float acc[3][4])
{
    for (int dy = 0; dy < 5; ++dy) {
        const int yy = y + dy - 2;
        const bool rowok = (yy >= 0 && yy < H);

        float pw[12], v0[12], v1[12], v2[12];
        if (rowok) {
            const int srow = r_i + dy;
            *reinterpret_cast<f32x4*>(&pw[0]) =
                *reinterpret_cast<const f32x4*>(&P[srow][4 * g_i]);
            *reinterpret_cast<f32x4*>(&pw[4]) =
                *reinterpret_cast<const f32x4*>(&P[srow][4 * g_i + 4]);
            *reinterpret_cast<f32x4*>(&pw[8]) =
                *reinterpret_cast<const f32x4*>(&P[srow][4 * g_i + 8]);
            const int imo = b * (6 * HW) + 3 * HW + yy * W;
            f4_win12(v0, im + imo, x);
            f4_win12(v1, im + imo + HW, x);
            f4_win12(v2, im + imo + 2 * HW, x);
        }

        // 5 mask planes per iteration: stores issued between loads and math.
#pragma unroll
        for (int kk = 0; kk < 5; ++kk) {
            const int k = dy * 5 + kk;
            nt_store4(mbase + k * HW, lab4[0] == k ? 1.f : 0.f, lab4[1] == k ? 1.f : 0.f,
                      lab4[2] == k ? 1.f : 0.f, lab4[3] == k ? 1.f : 0.f);
        }

        if (rowok) {
            int lw[12];
            float aw[12];
#pragma unroll
            for (int j = 2; j < 10; ++j) {
                const int l = (int)(pw[j] * 0.5f);
                lw[j] = l;
                aw[j] = pw[j] - 2.f * (float)l;
            }
#pragma unroll
            for (int dx = 0; dx < 5; ++dx) {
                const int base = (dy * 5 + dx) * 26;
#pragma unroll
                for (int i = 0; i < 4; ++i) {
                    const int li = i + dx + 2;
                    const float w = aw[li] * sk[base + lw[li]];
                    acc[0][i] = fmaf(w, v0[li], acc[0][i]);
                    acc[1][i] = fmaf(w, v1[li], acc[1][i]);
                    acc[2][i] = fmaf(w, v2[li], acc[2][i]);
                }
            }
        }
    }
}

__global__ __launch_bounds__(NTHR) void k_fused(
    const float* __restrict__ imF, const float* __restrict__ imB,
    const int* __restrict__ labF, const int* __restrict__ labB,
    const float* __restrict__ mk, float* __restrict__ out)
{
    __shared__ float sk[LUTN];
    __shared__ float pF[SROWS][SW];
    __shared__ float pB[SROWS][SW];

    for (int i = threadIdx.x; i < LUTN; i += NTHR) {
        const int tap = i / 26;
        const int l = i - tap * 26;
        sk[i] = (l < NCLS) ? mk[l * 25 + tap] : 0.0f;
    }
    __syncthreads();

    const int blk = blockIdx.x;
    const int by = blk % YT;
    const int b  = blk / YT;
    const int y0 = by * TY;
    const int t = threadIdx.x;
    const int r_i = t / GPR;   // 0..7
    const int g_i = t % GPR;   // 0..47

    // --- Phase A: stage packed (2*lab + appear); interior writes aux outputs ---
    float my_at[4];
    int lfa[4], lba[4];
    stage_unit<true>(r_i + 2, g_i, b, y0, labF, labB, sk, pF, pB, out, my_at, lfa, lba);
    if (t < 4 * GPR) {
        const int hr = t / GPR;                     // 0..3
        const int row = (hr < 2) ? hr : hr + TY;    // {0,1,10,11}
        float da[4]; int d1[4], d2[4];
        stage_unit<false>(row, t % GPR, b, y0, labF, labB, sk, pF, pB, out, da, d1, d2);
    } else if (t < 4 * GPR + 48) {
        const int h = t - 4 * GPR;                  // 0..47
        const int arr = h & 1, side = (h >> 1) & 1, row = h >> 2;  // row 0..11
        f32x4 s = {SENT, SENT, SENT, SENT};
        float* dst = arr ? &pB[row][side ? W + 4 : 0] : &pF[row][side ? W + 4 : 0];
        *reinterpret_cast<f32x4*>(dst) = s;
    }
    __syncthreads();

    // --- Phase B: conv with interleaved mask stores ---
    const int y = y0 + r_i;
    const int x = 4 * g_i;
    const int pix = b * HW + y * W + x;

    float accF[3][4] = {};
    float accB[3][4] = {};
    conv_img(pF, imF, sk, lfa, out + OFF_MASKF + b * (NCLS * HW) + y * W + x,
             b, y, x, r_i, g_i, accF);
    conv_img(pB, imB, sk, lba, out + OFF_MASKB + b * (NCLS * HW) + y * W + x,
             b, y, x, r_i, g_i, accB);

    float* pout = out + OFF_PRED + b * (3 * HW) + y * W + x;
#pragma unroll
    for (int c = 0; c < 3; ++c) {
        float p[4];
#pragma unroll
        for (int i = 0; i < 4; ++i)
            p[i] = my_at[i] * accF[c][i] + (1.f - my_at[i]) * accB[c][i];
        nt_store4(pout + c * HW, p[0], p[1], p[2], p[3]);
    }
}

extern "C" void kernel_launch(void* const* d_in, const int* in_sizes, int n_in,
                              void* d_out, int out_size, void* d_ws, size_t ws_size,
                              hipStream_t stream) {
    const float* imF  = (const float*)d_in[0];
    const float* imB  = (const float*)d_in[1];
    const int*   labF = (const int*)d_in[2];
    const int*   labB = (const int*)d_in[3];
    const float* mk   = (const float*)d_in[4];
    float* out = (float*)d_out;

    k_fused<<<NBLK, NTHR, 0, stream>>>(imF, imB, labF, labB, mk, out);
}